// Round 7
// baseline (354.943 us; speedup 1.0000x reference)
//
#include <hip/hip_runtime.h>
#include <hip/hip_bf16.h>

#define N_NODES 100000
#define E_EDGES 1600000
#define IN_DIM  128
#define HID     64
#define HEADS   4
#define NEG_SLOPE 0.2f
#define LN_EPS  1e-5f
#define LOG2E   1.4426950408889634f

#define BUCK_SHIFT 7
#define NODES_PER_BUCK 128
#define NBUCK ((N_NODES + NODES_PER_BUCK - 1) / NODES_PER_BUCK)   // 782
#define NBUCK_PAD 1024
#define PART_CHUNK 8192

__device__ __forceinline__ float bflo(unsigned u) { return __uint_as_float(u << 16); }
__device__ __forceinline__ float bfhi(unsigned u) { return __uint_as_float(u & 0xffff0000u); }
__device__ __forceinline__ unsigned packbf2(float a, float b) {
    unsigned ua = __float_as_uint(a), ub = __float_as_uint(b);
    ua += 0x7fffu + ((ua >> 16) & 1u);
    ub += 0x7fffu + ((ub >> 16) & 1u);
    return (ua >> 16) | (ub & 0xffff0000u);
}
// e pre-scaled by LOG2E; weight = exp(lrelu(e_orig)) = 2^(lrelu(e))
__device__ __forceinline__ float lrexp2(float e) {
    return __builtin_amdgcn_exp2f(fmaxf(e, NEG_SLOPE * e));
}

// ---- fused: h0 = relu(x @ Win + bin); hl0(bf16) = h0 @ Wg0; alpha0 ----
__global__ __launch_bounds__(256) void k_in_proj_fused(
        const float* __restrict__ x, const float* __restrict__ W,
        const float* __restrict__ bias,
        const float* __restrict__ W2g, const float* __restrict__ as_w,
        const float* __restrict__ ad_w,
        float* __restrict__ h, unsigned* __restrict__ hlb,
        float* __restrict__ as_o, float* __restrict__ ad_o) {
    __shared__ float Xs[32][132];     // 16.9 KB (reused as H2[32][68] later)
    __shared__ float Ws[128][64];     // 32 KB
    __shared__ float W2[64][64];      // 16 KB
    int t = threadIdx.x;
    const float4* W4 = (const float4*)W;
    float4* Ws4 = (float4*)&Ws[0][0];
    #pragma unroll
    for (int i = 0; i < 8; ++i) Ws4[t + 256 * i] = W4[t + 256 * i];
    const float4* W24 = (const float4*)W2g;
    float4* W2s4 = (float4*)&W2[0][0];
    #pragma unroll
    for (int i = 0; i < 4; ++i) W2s4[t + 256 * i] = W24[t + 256 * i];
    int base = blockIdx.x * 32;
    const float4* X4 = (const float4*)(x + (size_t)base * IN_DIM);
    #pragma unroll
    for (int i = 0; i < 4; ++i) {
        int f = t + 256 * i;
        int row = f >> 5, col4 = f & 31;
        ((float4*)&Xs[row][0])[col4] = X4[f];
    }
    __syncthreads();
    int r = t >> 4;
    int c = (t & 15) * 4;
    float4 bb = *(const float4*)(bias + c);
    float4 acc0 = bb, acc1 = bb;
    #pragma unroll 8
    for (int k = 0; k < 128; ++k) {
        float a0 = Xs[r][k];
        float a1 = Xs[r + 16][k];
        float4 b = *(const float4*)&Ws[k][c];
        acc0.x += a0 * b.x; acc0.y += a0 * b.y; acc0.z += a0 * b.z; acc0.w += a0 * b.w;
        acc1.x += a1 * b.x; acc1.y += a1 * b.y; acc1.z += a1 * b.z; acc1.w += a1 * b.w;
    }
    acc0.x = fmaxf(acc0.x, 0.f); acc0.y = fmaxf(acc0.y, 0.f);
    acc0.z = fmaxf(acc0.z, 0.f); acc0.w = fmaxf(acc0.w, 0.f);
    acc1.x = fmaxf(acc1.x, 0.f); acc1.y = fmaxf(acc1.y, 0.f);
    acc1.z = fmaxf(acc1.z, 0.f); acc1.w = fmaxf(acc1.w, 0.f);
    *(float4*)(h + (size_t)(base + r) * HID + c) = acc0;
    *(float4*)(h + (size_t)(base + r + 16) * HID + c) = acc1;
    __syncthreads();   // all Xs reads done; safe to overwrite
    float (*H2)[68] = (float(*)[68])Xs;
    *(float4*)&H2[r][c] = acc0;
    *(float4*)&H2[r + 16][c] = acc1;
    __syncthreads();
    // second GEMM: hl = h0 @ Wg0
    float4 s0v = {0.f,0.f,0.f,0.f}, s1v = {0.f,0.f,0.f,0.f};
    #pragma unroll 8
    for (int k = 0; k < 64; ++k) {
        float a0 = H2[r][k];
        float a1 = H2[r + 16][k];
        float4 b = *(const float4*)&W2[k][c];
        s0v.x += a0 * b.x; s0v.y += a0 * b.y; s0v.z += a0 * b.z; s0v.w += a0 * b.w;
        s1v.x += a1 * b.x; s1v.y += a1 * b.y; s1v.z += a1 * b.z; s1v.w += a1 * b.w;
    }
    uint2 p0, p1;
    p0.x = packbf2(s0v.x, s0v.y); p0.y = packbf2(s0v.z, s0v.w);
    p1.x = packbf2(s1v.x, s1v.y); p1.y = packbf2(s1v.z, s1v.w);
    ((uint2*)hlb)[(size_t)(base + r) * 16 + (c >> 2)] = p0;
    ((uint2*)hlb)[(size_t)(base + r + 16) * 16 + (c >> 2)] = p1;
    float4 A = *(const float4*)(as_w + c);
    float4 D = *(const float4*)(ad_w + c);
    A.x *= LOG2E; A.y *= LOG2E; A.z *= LOG2E; A.w *= LOG2E;
    D.x *= LOG2E; D.y *= LOG2E; D.z *= LOG2E; D.w *= LOG2E;
    float s0 = s0v.x * A.x + s0v.y * A.y + s0v.z * A.z + s0v.w * A.w;
    float d0 = s0v.x * D.x + s0v.y * D.y + s0v.z * D.z + s0v.w * D.w;
    float s1 = s1v.x * A.x + s1v.y * A.y + s1v.z * A.z + s1v.w * A.w;
    float d1 = s1v.x * D.x + s1v.y * D.y + s1v.z * D.z + s1v.w * D.w;
    #pragma unroll
    for (int off = 1; off < 4; off <<= 1) {
        s0 += __shfl_xor(s0, off); d0 += __shfl_xor(d0, off);
        s1 += __shfl_xor(s1, off); d1 += __shfl_xor(d1, off);
    }
    if ((t & 3) == 0) {
        int head = (t & 15) >> 2;
        as_o[(size_t)(base + r) * HEADS + head] = s0;
        ad_o[(size_t)(base + r) * HEADS + head] = d0;
        as_o[(size_t)(base + r + 16) * HEADS + head] = s1;
        ad_o[(size_t)(base + r + 16) * HEADS + head] = d1;
    }
}

// ---- kernel B: hl(bf16) = h @ Wg + per-(node,head) alpha reductions ----
__global__ __launch_bounds__(256) void k_gat_lin(
        const float* __restrict__ h, const float* __restrict__ W,
        const float* __restrict__ as_w, const float* __restrict__ ad_w,
        unsigned* __restrict__ hlb, float* __restrict__ as_o, float* __restrict__ ad_o) {
    __shared__ float Xs[32][68];
    __shared__ float Ws[64][64];
    int t = threadIdx.x;
    const float4* W4 = (const float4*)W;
    float4* Ws4 = (float4*)&Ws[0][0];
    #pragma unroll
    for (int i = 0; i < 4; ++i) Ws4[t + 256 * i] = W4[t + 256 * i];
    int base = blockIdx.x * 32;
    const float4* X4 = (const float4*)(h + (size_t)base * HID);
    #pragma unroll
    for (int i = 0; i < 2; ++i) {
        int f = t + 256 * i;
        int row = f >> 4, col4 = f & 15;
        ((float4*)&Xs[row][0])[col4] = X4[f];
    }
    __syncthreads();
    int r = t >> 4;
    int c = (t & 15) * 4;
    float4 acc0 = {0.f, 0.f, 0.f, 0.f}, acc1 = {0.f, 0.f, 0.f, 0.f};
    #pragma unroll 8
    for (int k = 0; k < 64; ++k) {
        float a0 = Xs[r][k];
        float a1 = Xs[r + 16][k];
        float4 b = *(const float4*)&Ws[k][c];
        acc0.x += a0 * b.x; acc0.y += a0 * b.y; acc0.z += a0 * b.z; acc0.w += a0 * b.w;
        acc1.x += a1 * b.x; acc1.y += a1 * b.y; acc1.z += a1 * b.z; acc1.w += a1 * b.w;
    }
    uint2 p0, p1;
    p0.x = packbf2(acc0.x, acc0.y); p0.y = packbf2(acc0.z, acc0.w);
    p1.x = packbf2(acc1.x, acc1.y); p1.y = packbf2(acc1.z, acc1.w);
    ((uint2*)hlb)[(size_t)(base + r) * 16 + (c >> 2)] = p0;
    ((uint2*)hlb)[(size_t)(base + r + 16) * 16 + (c >> 2)] = p1;
    float4 A = *(const float4*)(as_w + c);
    float4 D = *(const float4*)(ad_w + c);
    A.x *= LOG2E; A.y *= LOG2E; A.z *= LOG2E; A.w *= LOG2E;
    D.x *= LOG2E; D.y *= LOG2E; D.z *= LOG2E; D.w *= LOG2E;
    float s0 = acc0.x * A.x + acc0.y * A.y + acc0.z * A.z + acc0.w * A.w;
    float d0 = acc0.x * D.x + acc0.y * D.y + acc0.z * D.z + acc0.w * D.w;
    float s1 = acc1.x * A.x + acc1.y * A.y + acc1.z * A.z + acc1.w * A.w;
    float d1 = acc1.x * D.x + acc1.y * D.y + acc1.z * D.z + acc1.w * D.w;
    #pragma unroll
    for (int off = 1; off < 4; off <<= 1) {
        s0 += __shfl_xor(s0, off); d0 += __shfl_xor(d0, off);
        s1 += __shfl_xor(s1, off); d1 += __shfl_xor(d1, off);
    }
    if ((t & 3) == 0) {
        int head = (t & 15) >> 2;
        as_o[(size_t)(base + r) * HEADS + head] = s0;
        ad_o[(size_t)(base + r) * HEADS + head] = d0;
        as_o[(size_t)(base + r + 16) * HEADS + head] = s1;
        ad_o[(size_t)(base + r + 16) * HEADS + head] = d1;
    }
}

// ---- CSR build, bucketized (bucket = dst >> 7 = 128 consecutive nodes) ----
__global__ __launch_bounds__(256) void k_bhist(const int* __restrict__ dstp,
                                               int* __restrict__ bcnt) {
    __shared__ int c[NBUCK_PAD];
    int t = threadIdx.x;
    for (int i = t; i < NBUCK_PAD; i += 256) c[i] = 0;
    __syncthreads();
    for (int i = blockIdx.x * 256 + t; i < E_EDGES; i += gridDim.x * 256)
        atomicAdd(&c[dstp[i] >> BUCK_SHIFT], 1);
    __syncthreads();
    for (int i = t; i < NBUCK_PAD; i += 256) {
        int v = c[i];
        if (v) atomicAdd(bcnt + i, v);
    }
}

__global__ __launch_bounds__(1024) void k_bscan(const int* __restrict__ bcnt,
                                                int* __restrict__ bbase,
                                                int* __restrict__ bcur) {
    __shared__ int s[NBUCK_PAD];
    int tid = threadIdx.x;
    int v = bcnt[tid];
    s[tid] = v;
    __syncthreads();
    for (int off = 1; off < NBUCK_PAD; off <<= 1) {
        int t = (tid >= off) ? s[tid - off] : 0;
        __syncthreads();
        s[tid] += t;
        __syncthreads();
    }
    int excl = s[tid] - v;
    bbase[tid] = excl;
    bcur[tid] = excl;
    if (tid == NBUCK_PAD - 1) bbase[NBUCK_PAD] = s[tid];
}

// ebuf element: src (17 bits) | dst_low7 << 17
__global__ __launch_bounds__(256) void k_part(const int* __restrict__ srcp,
                                              const int* __restrict__ dstp,
                                              int* __restrict__ bcur,
                                              unsigned* __restrict__ ebuf) {
    __shared__ int cnt[NBUCK_PAD];
    __shared__ int gbase[NBUCK_PAD];
    int t = threadIdx.x;
    for (int i = t; i < NBUCK_PAD; i += 256) cnt[i] = 0;
    int e0 = blockIdx.x * PART_CHUNK;
    int e1 = min(e0 + PART_CHUNK, E_EDGES);
    __syncthreads();
    for (int i = e0 + t; i < e1; i += 256)
        atomicAdd(&cnt[dstp[i] >> BUCK_SHIFT], 1);
    __syncthreads();
    for (int b = t; b < NBUCK_PAD; b += 256) {
        int c = cnt[b];
        gbase[b] = c ? atomicAdd(bcur + b, c) : 0;
        cnt[b] = 0;
    }
    __syncthreads();
    for (int i = e0 + t; i < e1; i += 256) {
        int d = dstp[i];
        int b = d >> BUCK_SHIFT;
        int pos = gbase[b] + atomicAdd(&cnt[b], 1);
        ebuf[pos] = (unsigned)srcp[i] | ((unsigned)(d & 127) << 17);
    }
}

__global__ __launch_bounds__(256) void k_fin(const int* __restrict__ bbase,
                                             const unsigned* __restrict__ ebuf,
                                             int* __restrict__ row,
                                             int* __restrict__ ssrc) {
    __shared__ int cnt[NODES_PER_BUCK];
    __shared__ int sc[NODES_PER_BUCK];
    __shared__ int rbase[NODES_PER_BUCK];
    int t = threadIdx.x;
    int b = blockIdx.x;
    int start = bbase[b], end = bbase[b + 1];
    int nb0 = b << BUCK_SHIFT;
    if (t < NODES_PER_BUCK) cnt[t] = 0;
    __syncthreads();
    for (int i = start + t; i < end; i += 256)
        atomicAdd(&cnt[ebuf[i] >> 17], 1);
    __syncthreads();
    if (t < NODES_PER_BUCK) sc[t] = cnt[t];
    __syncthreads();
    for (int off = 1; off < NODES_PER_BUCK; off <<= 1) {
        int v = (t < NODES_PER_BUCK && t >= off) ? sc[t - off] : 0;
        __syncthreads();
        if (t < NODES_PER_BUCK) sc[t] += v;
        __syncthreads();
    }
    if (t < NODES_PER_BUCK) {
        int rb = start + sc[t] - cnt[t];
        rbase[t] = rb;
        int n = nb0 + t;
        if (n < N_NODES) row[n] = rb;
        cnt[t] = 0;
    }
    if (b == NBUCK - 1 && t == 0) row[N_NODES] = E_EDGES;
    __syncthreads();
    for (int i = start + t; i < end; i += 256) {
        unsigned p = ebuf[i];
        int l = (int)(p >> 17);
        int slot = rbase[l] + atomicAdd(&cnt[l], 1);
        ssrc[slot] = (int)(p & 0x1FFFFu);
    }
}

// ---- fused aggregation: wave/node, 4 groups x 16 lanes, uint2 loads,
//      32-bit byte-offset addressing, unroll2 -> 8 edges in flight ----
__global__ __launch_bounds__(256) void k_gat_agg(
        const int* __restrict__ row, const int* __restrict__ ssrc,
        const float* __restrict__ as_, const float* __restrict__ ad_,
        const unsigned* __restrict__ hlb, const float* __restrict__ hres,
        const float* __restrict__ bg, const float* __restrict__ g,
        const float* __restrict__ b, float* __restrict__ hout,
        const float* __restrict__ Wout, const float* __restrict__ bout,
        float* __restrict__ out, int last) {
    int gid = blockIdx.x * blockDim.x + threadIdx.x;
    int n = gid >> 6;
    if (n >= N_NODES) return;
    int lane = threadIdx.x & 63;
    int grp = lane >> 4;          // 0..3: edge group
    int q   = lane & 15;          // channels 4q..4q+3
    int head = q >> 2;
    const char* hlbc = (const char*)hlb;   // row stride 128 B
    const char* asc  = (const char*)as_;   // row stride 16 B
    unsigned qb = (unsigned)q * 8u;
    unsigned hb = (unsigned)head * 4u;
    float adh = ad_[n * 4 + head];
    float acc0 = 0.f, acc1 = 0.f, acc2 = 0.f, acc3 = 0.f, z = 0.f;
    if (grp == 0) {   // self loop
        float w = lrexp2(*(const float*)(asc + ((unsigned)n * 16u + hb)) + adh);
        uint2 u = *(const uint2*)(hlbc + ((unsigned)n * 128u + qb));
        acc0 = w * bflo(u.x); acc1 = w * bfhi(u.x);
        acc2 = w * bflo(u.y); acc3 = w * bfhi(u.y);
        z = w;
    }
    int j = row[n] + grp;
    int jend = row[n + 1];
    for (; j + 4 < jend; j += 8) {
        unsigned s0 = (unsigned)ssrc[j], s1 = (unsigned)ssrc[j + 4];
        float wa = lrexp2(*(const float*)(asc + (s0 * 16u + hb)) + adh);
        float wb = lrexp2(*(const float*)(asc + (s1 * 16u + hb)) + adh);
        uint2 ua = *(const uint2*)(hlbc + (s0 * 128u + qb));
        uint2 ub = *(const uint2*)(hlbc + (s1 * 128u + qb));
        acc0 += wa * bflo(ua.x) + wb * bflo(ub.x);
        acc1 += wa * bfhi(ua.x) + wb * bfhi(ub.x);
        acc2 += wa * bflo(ua.y) + wb * bflo(ub.y);
        acc3 += wa * bfhi(ua.y) + wb * bfhi(ub.y);
        z += wa + wb;
    }
    if (j < jend) {
        unsigned s0 = (unsigned)ssrc[j];
        float wa = lrexp2(*(const float*)(asc + (s0 * 16u + hb)) + adh);
        uint2 ua = *(const uint2*)(hlbc + (s0 * 128u + qb));
        acc0 += wa * bflo(ua.x);
        acc1 += wa * bfhi(ua.x);
        acc2 += wa * bflo(ua.y);
        acc3 += wa * bfhi(ua.y);
        z += wa;
    }
    // merge the 4 edge-groups (lanes with equal q)
    acc0 += __shfl_xor(acc0, 16); acc0 += __shfl_xor(acc0, 32);
    acc1 += __shfl_xor(acc1, 16); acc1 += __shfl_xor(acc1, 32);
    acc2 += __shfl_xor(acc2, 16); acc2 += __shfl_xor(acc2, 32);
    acc3 += __shfl_xor(acc3, 16); acc3 += __shfl_xor(acc3, 32);
    z    += __shfl_xor(z, 16);    z    += __shfl_xor(z, 32);
    float rz = 1.f / (z + 1e-16f);
    float4 bgv = ((const float4*)bg)[q];
    float v0 = acc0 * rz + bgv.x;
    float v1 = acc1 * rz + bgv.y;
    float v2 = acc2 * rz + bgv.z;
    float v3 = acc3 * rz + bgv.w;
    float ssum = v0 + v1 + v2 + v3;
    #pragma unroll
    for (int off = 1; off < 16; off <<= 1) ssum += __shfl_xor(ssum, off);
    float mu = ssum * (1.f / 64.f);
    float d0 = v0 - mu, d1 = v1 - mu, d2 = v2 - mu, d3 = v3 - mu;
    float vs = d0 * d0 + d1 * d1 + d2 * d2 + d3 * d3;
    #pragma unroll
    for (int off = 1; off < 16; off <<= 1) vs += __shfl_xor(vs, off);
    float rstd = rsqrtf(vs * (1.f / 64.f) + LN_EPS);
    float4 gv = ((const float4*)g)[q];
    float4 bv = ((const float4*)b)[q];
    float4 hr = ((const float4*)hres)[(size_t)n * 16 + q];
    float y0 = fmaxf(d0 * rstd * gv.x + bv.x, 0.f) + hr.x;
    float y1 = fmaxf(d1 * rstd * gv.y + bv.y, 0.f) + hr.y;
    float y2 = fmaxf(d2 * rstd * gv.z + bv.z, 0.f) + hr.z;
    float y3 = fmaxf(d3 * rstd * gv.w + bv.w, 0.f) + hr.w;
    if (!last) {
        if (grp == 0) {
            float4 o; o.x = y0; o.y = y1; o.z = y2; o.w = y3;
            ((float4*)hout)[(size_t)n * 16 + q] = o;
        }
    } else {
        float4 wv = ((const float4*)Wout)[q];
        float pp = y0 * wv.x + y1 * wv.y + y2 * wv.z + y3 * wv.w;
        #pragma unroll
        for (int off = 1; off < 16; off <<= 1) pp += __shfl_xor(pp, off);
        if (lane == 0) out[n] = pp + bout[0];
    }
}

extern "C" void kernel_launch(void* const* d_in, const int* in_sizes, int n_in,
                              void* d_out, int out_size, void* d_ws, size_t ws_size,
                              hipStream_t stream) {
    const float* x     = (const float*)d_in[0];
    const int*   ei    = (const int*)  d_in[1];
    const float* Win   = (const float*)d_in[2];
    const float* bin_  = (const float*)d_in[3];
    const float* Wg    = (const float*)d_in[4];
    const float* att_s = (const float*)d_in[5];
    const float* att_d = (const float*)d_in[6];
    const float* bg    = (const float*)d_in[7];
    const float* lng   = (const float*)d_in[8];
    const float* lnb   = (const float*)d_in[9];
    const float* Wout  = (const float*)d_in[10];
    const float* bout  = (const float*)d_in[11];
    float* out = (float*)d_out;

    float* hA   = (float*)d_ws;                        // h (layer input / residual)
    float* hC   = hA + (size_t)N_NODES * 64;           // h (layer output)
    unsigned* hlb = (unsigned*)(hC + (size_t)N_NODES * 64);  // bf16x2 [N][32]
    float* as_  = (float*)(hlb + (size_t)N_NODES * 32);
    float* ad_  = as_ + (size_t)N_NODES * 4;
    int* row    = (int*)(ad_ + (size_t)N_NODES * 4);   // N+1
    int* bcnt   = row + (N_NODES + 1);                 // 1024
    int* bbase  = bcnt + NBUCK_PAD;                    // 1025
    int* bcur   = bbase + (NBUCK_PAD + 1);             // 1024
    int* ssrc   = bcur + NBUCK_PAD;                    // E
    unsigned* ebuf = (unsigned*)(ssrc + E_EDGES);      // E packed

    const int* srcp = ei;
    const int* dstp = ei + E_EDGES;

    hipMemsetAsync(bcnt, 0, NBUCK_PAD * sizeof(int), stream);
    k_bhist<<<256, 256, 0, stream>>>(dstp, bcnt);
    k_bscan<<<1, NBUCK_PAD, 0, stream>>>(bcnt, bbase, bcur);
    k_part<<<(E_EDGES + PART_CHUNK - 1) / PART_CHUNK, 256, 0, stream>>>(srcp, dstp, bcur, ebuf);
    k_fin<<<NBUCK, 256, 0, stream>>>(bbase, ebuf, row, ssrc);

    k_in_proj_fused<<<N_NODES / 32, 256, 0, stream>>>(
        x, Win, bin_, Wg, att_s, att_d, hA, hlb, as_, ad_);

    const int aggBlocks = (N_NODES * 64 + 255) / 256;
    for (int L = 0; L < 3; ++L) {
        if (L > 0) {
            k_gat_lin<<<N_NODES / 32, 256, 0, stream>>>(hA, Wg + L * 64 * 64,
                                                att_s + L * 64, att_d + L * 64,
                                                hlb, as_, ad_);
        }
        k_gat_agg<<<aggBlocks, 256, 0, stream>>>(row, ssrc, as_, ad_, hlb, hA,
                                                 bg + L * 64, lng + L * 64, lnb + L * 64,
                                                 hC, Wout, bout, out, (L == 2) ? 1 : 0);
        float* t = hA; hA = hC; hC = t;
    }
}

// Round 8
// 343.551 us; speedup vs baseline: 1.0332x; 1.0332x over previous
//
#include <hip/hip_runtime.h>
#include <hip/hip_bf16.h>

#define N_NODES 100000
#define E_EDGES 1600000
#define IN_DIM  128
#define HID     64
#define HEADS   4
#define NEG_SLOPE 0.2f
#define LN_EPS  1e-5f
#define LOG2E   1.4426950408889634f

#define BUCK_SHIFT 7
#define NODES_PER_BUCK 128
#define NBUCK ((N_NODES + NODES_PER_BUCK - 1) / NODES_PER_BUCK)   // 782
#define NBUCK_PAD 1024
#define PART_CHUNK 8192

__device__ __forceinline__ float bflo(unsigned u) { return __uint_as_float(u << 16); }
__device__ __forceinline__ float bfhi(unsigned u) { return __uint_as_float(u & 0xffff0000u); }
__device__ __forceinline__ unsigned packbf2(float a, float b) {
    unsigned ua = __float_as_uint(a), ub = __float_as_uint(b);
    ua += 0x7fffu + ((ua >> 16) & 1u);
    ub += 0x7fffu + ((ub >> 16) & 1u);
    return (ua >> 16) | (ub & 0xffff0000u);
}
// e pre-scaled by LOG2E; weight = exp(lrelu(e_orig)) = 2^(lrelu(e))
__device__ __forceinline__ float lrexp2(float e) {
    return __builtin_amdgcn_exp2f(fmaxf(e, NEG_SLOPE * e));
}

// ---- fused: h0 = relu(x @ Win + bin); hl0(bf16) = h0 @ Wg0; alpha0 ----
__global__ __launch_bounds__(256) void k_in_proj_fused(
        const float* __restrict__ x, const float* __restrict__ W,
        const float* __restrict__ bias,
        const float* __restrict__ W2g, const float* __restrict__ as_w,
        const float* __restrict__ ad_w,
        float* __restrict__ h, unsigned* __restrict__ hlb,
        float* __restrict__ as_o, float* __restrict__ ad_o) {
    __shared__ float Xs[32][132];     // reused as H2[32][68] later
    __shared__ float Ws[128][64];
    __shared__ float W2[64][64];
    int t = threadIdx.x;
    const float4* W4 = (const float4*)W;
    float4* Ws4 = (float4*)&Ws[0][0];
    #pragma unroll
    for (int i = 0; i < 8; ++i) Ws4[t + 256 * i] = W4[t + 256 * i];
    const float4* W24 = (const float4*)W2g;
    float4* W2s4 = (float4*)&W2[0][0];
    #pragma unroll
    for (int i = 0; i < 4; ++i) W2s4[t + 256 * i] = W24[t + 256 * i];
    int base = blockIdx.x * 32;
    const float4* X4 = (const float4*)(x + (size_t)base * IN_DIM);
    #pragma unroll
    for (int i = 0; i < 4; ++i) {
        int f = t + 256 * i;
        int row = f >> 5, col4 = f & 31;
        ((float4*)&Xs[row][0])[col4] = X4[f];
    }
    __syncthreads();
    int r = t >> 4;
    int c = (t & 15) * 4;
    float4 bb = *(const float4*)(bias + c);
    float4 acc0 = bb, acc1 = bb;
    #pragma unroll 8
    for (int k = 0; k < 128; ++k) {
        float a0 = Xs[r][k];
        float a1 = Xs[r + 16][k];
        float4 b = *(const float4*)&Ws[k][c];
        acc0.x += a0 * b.x; acc0.y += a0 * b.y; acc0.z += a0 * b.z; acc0.w += a0 * b.w;
        acc1.x += a1 * b.x; acc1.y += a1 * b.y; acc1.z += a1 * b.z; acc1.w += a1 * b.w;
    }
    acc0.x = fmaxf(acc0.x, 0.f); acc0.y = fmaxf(acc0.y, 0.f);
    acc0.z = fmaxf(acc0.z, 0.f); acc0.w = fmaxf(acc0.w, 0.f);
    acc1.x = fmaxf(acc1.x, 0.f); acc1.y = fmaxf(acc1.y, 0.f);
    acc1.z = fmaxf(acc1.z, 0.f); acc1.w = fmaxf(acc1.w, 0.f);
    *(float4*)(h + (size_t)(base + r) * HID + c) = acc0;
    *(float4*)(h + (size_t)(base + r + 16) * HID + c) = acc1;
    __syncthreads();
    float (*H2)[68] = (float(*)[68])Xs;
    *(float4*)&H2[r][c] = acc0;
    *(float4*)&H2[r + 16][c] = acc1;
    __syncthreads();
    float4 s0v = {0.f,0.f,0.f,0.f}, s1v = {0.f,0.f,0.f,0.f};
    #pragma unroll 8
    for (int k = 0; k < 64; ++k) {
        float a0 = H2[r][k];
        float a1 = H2[r + 16][k];
        float4 b = *(const float4*)&W2[k][c];
        s0v.x += a0 * b.x; s0v.y += a0 * b.y; s0v.z += a0 * b.z; s0v.w += a0 * b.w;
        s1v.x += a1 * b.x; s1v.y += a1 * b.y; s1v.z += a1 * b.z; s1v.w += a1 * b.w;
    }
    uint2 p0, p1;
    p0.x = packbf2(s0v.x, s0v.y); p0.y = packbf2(s0v.z, s0v.w);
    p1.x = packbf2(s1v.x, s1v.y); p1.y = packbf2(s1v.z, s1v.w);
    ((uint2*)hlb)[(size_t)(base + r) * 16 + (c >> 2)] = p0;
    ((uint2*)hlb)[(size_t)(base + r + 16) * 16 + (c >> 2)] = p1;
    float4 A = *(const float4*)(as_w + c);
    float4 D = *(const float4*)(ad_w + c);
    A.x *= LOG2E; A.y *= LOG2E; A.z *= LOG2E; A.w *= LOG2E;
    D.x *= LOG2E; D.y *= LOG2E; D.z *= LOG2E; D.w *= LOG2E;
    float s0 = s0v.x * A.x + s0v.y * A.y + s0v.z * A.z + s0v.w * A.w;
    float d0 = s0v.x * D.x + s0v.y * D.y + s0v.z * D.z + s0v.w * D.w;
    float s1 = s1v.x * A.x + s1v.y * A.y + s1v.z * A.z + s1v.w * A.w;
    float d1 = s1v.x * D.x + s1v.y * D.y + s1v.z * D.z + s1v.w * D.w;
    #pragma unroll
    for (int off = 1; off < 4; off <<= 1) {
        s0 += __shfl_xor(s0, off); d0 += __shfl_xor(d0, off);
        s1 += __shfl_xor(s1, off); d1 += __shfl_xor(d1, off);
    }
    if ((t & 3) == 0) {
        int head = (t & 15) >> 2;
        as_o[(size_t)(base + r) * HEADS + head] = s0;
        ad_o[(size_t)(base + r) * HEADS + head] = d0;
        as_o[(size_t)(base + r + 16) * HEADS + head] = s1;
        ad_o[(size_t)(base + r + 16) * HEADS + head] = d1;
    }
}

// ---- kernel B: hl(bf16) = h @ Wg + per-(node,head) alpha reductions ----
__global__ __launch_bounds__(256) void k_gat_lin(
        const float* __restrict__ h, const float* __restrict__ W,
        const float* __restrict__ as_w, const float* __restrict__ ad_w,
        unsigned* __restrict__ hlb, float* __restrict__ as_o, float* __restrict__ ad_o) {
    __shared__ float Xs[32][68];
    __shared__ float Ws[64][64];
    int t = threadIdx.x;
    const float4* W4 = (const float4*)W;
    float4* Ws4 = (float4*)&Ws[0][0];
    #pragma unroll
    for (int i = 0; i < 4; ++i) Ws4[t + 256 * i] = W4[t + 256 * i];
    int base = blockIdx.x * 32;
    const float4* X4 = (const float4*)(h + (size_t)base * HID);
    #pragma unroll
    for (int i = 0; i < 2; ++i) {
        int f = t + 256 * i;
        int row = f >> 4, col4 = f & 15;
        ((float4*)&Xs[row][0])[col4] = X4[f];
    }
    __syncthreads();
    int r = t >> 4;
    int c = (t & 15) * 4;
    float4 acc0 = {0.f, 0.f, 0.f, 0.f}, acc1 = {0.f, 0.f, 0.f, 0.f};
    #pragma unroll 8
    for (int k = 0; k < 64; ++k) {
        float a0 = Xs[r][k];
        float a1 = Xs[r + 16][k];
        float4 b = *(const float4*)&Ws[k][c];
        acc0.x += a0 * b.x; acc0.y += a0 * b.y; acc0.z += a0 * b.z; acc0.w += a0 * b.w;
        acc1.x += a1 * b.x; acc1.y += a1 * b.y; acc1.z += a1 * b.z; acc1.w += a1 * b.w;
    }
    uint2 p0, p1;
    p0.x = packbf2(acc0.x, acc0.y); p0.y = packbf2(acc0.z, acc0.w);
    p1.x = packbf2(acc1.x, acc1.y); p1.y = packbf2(acc1.z, acc1.w);
    ((uint2*)hlb)[(size_t)(base + r) * 16 + (c >> 2)] = p0;
    ((uint2*)hlb)[(size_t)(base + r + 16) * 16 + (c >> 2)] = p1;
    float4 A = *(const float4*)(as_w + c);
    float4 D = *(const float4*)(ad_w + c);
    A.x *= LOG2E; A.y *= LOG2E; A.z *= LOG2E; A.w *= LOG2E;
    D.x *= LOG2E; D.y *= LOG2E; D.z *= LOG2E; D.w *= LOG2E;
    float s0 = acc0.x * A.x + acc0.y * A.y + acc0.z * A.z + acc0.w * A.w;
    float d0 = acc0.x * D.x + acc0.y * D.y + acc0.z * D.z + acc0.w * D.w;
    float s1 = acc1.x * A.x + acc1.y * A.y + acc1.z * A.z + acc1.w * A.w;
    float d1 = acc1.x * D.x + acc1.y * D.y + acc1.z * D.z + acc1.w * D.w;
    #pragma unroll
    for (int off = 1; off < 4; off <<= 1) {
        s0 += __shfl_xor(s0, off); d0 += __shfl_xor(d0, off);
        s1 += __shfl_xor(s1, off); d1 += __shfl_xor(d1, off);
    }
    if ((t & 3) == 0) {
        int head = (t & 15) >> 2;
        as_o[(size_t)(base + r) * HEADS + head] = s0;
        ad_o[(size_t)(base + r) * HEADS + head] = d0;
        as_o[(size_t)(base + r + 16) * HEADS + head] = s1;
        ad_o[(size_t)(base + r + 16) * HEADS + head] = d1;
    }
}

// ---- CSR build, bucketized (bucket = dst >> 7 = 128 consecutive nodes) ----
__global__ __launch_bounds__(256) void k_bhist(const int* __restrict__ dstp,
                                               int* __restrict__ bcnt) {
    __shared__ int c[NBUCK_PAD];
    int t = threadIdx.x;
    for (int i = t; i < NBUCK_PAD; i += 256) c[i] = 0;
    __syncthreads();
    for (int i = blockIdx.x * 256 + t; i < E_EDGES; i += gridDim.x * 256)
        atomicAdd(&c[dstp[i] >> BUCK_SHIFT], 1);
    __syncthreads();
    for (int i = t; i < NBUCK_PAD; i += 256) {
        int v = c[i];
        if (v) atomicAdd(bcnt + i, v);
    }
}

__global__ __launch_bounds__(1024) void k_bscan(const int* __restrict__ bcnt,
                                                int* __restrict__ bbase,
                                                int* __restrict__ bcur) {
    __shared__ int s[NBUCK_PAD];
    int tid = threadIdx.x;
    int v = bcnt[tid];
    s[tid] = v;
    __syncthreads();
    for (int off = 1; off < NBUCK_PAD; off <<= 1) {
        int t = (tid >= off) ? s[tid - off] : 0;
        __syncthreads();
        s[tid] += t;
        __syncthreads();
    }
    int excl = s[tid] - v;
    bbase[tid] = excl;
    bcur[tid] = excl;
    if (tid == NBUCK_PAD - 1) bbase[NBUCK_PAD] = s[tid];
}

// ebuf element: src (17 bits) | dst_low7 << 17
__global__ __launch_bounds__(256) void k_part(const int* __restrict__ srcp,
                                              const int* __restrict__ dstp,
                                              int* __restrict__ bcur,
                                              unsigned* __restrict__ ebuf) {
    __shared__ int cnt[NBUCK_PAD];
    __shared__ int gbase[NBUCK_PAD];
    int t = threadIdx.x;
    for (int i = t; i < NBUCK_PAD; i += 256) cnt[i] = 0;
    int e0 = blockIdx.x * PART_CHUNK;
    int e1 = min(e0 + PART_CHUNK, E_EDGES);
    __syncthreads();
    for (int i = e0 + t; i < e1; i += 256)
        atomicAdd(&cnt[dstp[i] >> BUCK_SHIFT], 1);
    __syncthreads();
    for (int b = t; b < NBUCK_PAD; b += 256) {
        int c = cnt[b];
        gbase[b] = c ? atomicAdd(bcur + b, c) : 0;
        cnt[b] = 0;
    }
    __syncthreads();
    for (int i = e0 + t; i < e1; i += 256) {
        int d = dstp[i];
        int b = d >> BUCK_SHIFT;
        int pos = gbase[b] + atomicAdd(&cnt[b], 1);
        ebuf[pos] = (unsigned)srcp[i] | ((unsigned)(d & 127) << 17);
    }
}

__global__ __launch_bounds__(256) void k_fin(const int* __restrict__ bbase,
                                             const unsigned* __restrict__ ebuf,
                                             int* __restrict__ row,
                                             int* __restrict__ ssrc) {
    __shared__ int cnt[NODES_PER_BUCK];
    __shared__ int sc[NODES_PER_BUCK];
    __shared__ int rbase[NODES_PER_BUCK];
    int t = threadIdx.x;
    int b = blockIdx.x;
    int start = bbase[b], end = bbase[b + 1];
    int nb0 = b << BUCK_SHIFT;
    if (t < NODES_PER_BUCK) cnt[t] = 0;
    __syncthreads();
    for (int i = start + t; i < end; i += 256)
        atomicAdd(&cnt[ebuf[i] >> 17], 1);
    __syncthreads();
    if (t < NODES_PER_BUCK) sc[t] = cnt[t];
    __syncthreads();
    for (int off = 1; off < NODES_PER_BUCK; off <<= 1) {
        int v = (t < NODES_PER_BUCK && t >= off) ? sc[t - off] : 0;
        __syncthreads();
        if (t < NODES_PER_BUCK) sc[t] += v;
        __syncthreads();
    }
    if (t < NODES_PER_BUCK) {
        int rb = start + sc[t] - cnt[t];
        rbase[t] = rb;
        int n = nb0 + t;
        if (n < N_NODES) row[n] = rb;
        cnt[t] = 0;
    }
    if (b == NBUCK - 1 && t == 0) row[N_NODES] = E_EDGES;
    __syncthreads();
    for (int i = start + t; i < end; i += 256) {
        unsigned p = ebuf[i];
        int l = (int)(p >> 17);
        int slot = rbase[l] + atomicAdd(&cnt[l], 1);
        ssrc[slot] = (int)(p & 0x1FFFFu);
    }
}

// ---- fused aggregation: wave/node, 8 groups x 8 lanes, uint4 loads,
//      unroll2 -> 16 edges in flight; + bias + LN + ReLU + residual
//      (+ final projection on last layer). ----
__global__ __launch_bounds__(256) void k_gat_agg(
        const int* __restrict__ row, const int* __restrict__ ssrc,
        const float* __restrict__ as_, const float* __restrict__ ad_,
        const unsigned* __restrict__ hlb, const float* __restrict__ hres,
        const float* __restrict__ bg, const float* __restrict__ g,
        const float* __restrict__ b, float* __restrict__ hout,
        const float* __restrict__ Wout, const float* __restrict__ bout,
        float* __restrict__ out, int last) {
    int gid = blockIdx.x * blockDim.x + threadIdx.x;
    int n = gid >> 6;
    if (n >= N_NODES) return;
    int lane = threadIdx.x & 63;
    int grp = lane >> 3;          // 0..7: edge group
    int q   = lane & 7;           // channels 8q..8q+7
    int head = q >> 1;
    const char* hlbc = (const char*)hlb;   // row stride 128 B
    const char* asc  = (const char*)as_;   // row stride 16 B
    unsigned qb = (unsigned)q * 16u;
    unsigned hb = (unsigned)head * 4u;
    float adh = ad_[n * 4 + head];
    float acc[8];
    #pragma unroll
    for (int i = 0; i < 8; ++i) acc[i] = 0.f;
    float z = 0.f;
    if (grp == 0) {   // self loop
        float w = lrexp2(*(const float*)(asc + ((unsigned)n * 16u + hb)) + adh);
        uint4 u = *(const uint4*)(hlbc + ((unsigned)n * 128u + qb));
        acc[0] = w * bflo(u.x); acc[1] = w * bfhi(u.x);
        acc[2] = w * bflo(u.y); acc[3] = w * bfhi(u.y);
        acc[4] = w * bflo(u.z); acc[5] = w * bfhi(u.z);
        acc[6] = w * bflo(u.w); acc[7] = w * bfhi(u.w);
        z = w;
    }
    int j = row[n] + grp;
    int jend = row[n + 1];
    for (; j + 8 < jend; j += 16) {
        unsigned s0 = (unsigned)ssrc[j], s1 = (unsigned)ssrc[j + 8];
        float wa = lrexp2(*(const float*)(asc + (s0 * 16u + hb)) + adh);
        float wb = lrexp2(*(const float*)(asc + (s1 * 16u + hb)) + adh);
        uint4 ua = *(const uint4*)(hlbc + (s0 * 128u + qb));
        uint4 ub = *(const uint4*)(hlbc + (s1 * 128u + qb));
        acc[0] += wa * bflo(ua.x) + wb * bflo(ub.x);
        acc[1] += wa * bfhi(ua.x) + wb * bfhi(ub.x);
        acc[2] += wa * bflo(ua.y) + wb * bflo(ub.y);
        acc[3] += wa * bfhi(ua.y) + wb * bfhi(ub.y);
        acc[4] += wa * bflo(ua.z) + wb * bflo(ub.z);
        acc[5] += wa * bfhi(ua.z) + wb * bfhi(ub.z);
        acc[6] += wa * bflo(ua.w) + wb * bflo(ub.w);
        acc[7] += wa * bfhi(ua.w) + wb * bfhi(ub.w);
        z += wa + wb;
    }
    if (j < jend) {
        unsigned s0 = (unsigned)ssrc[j];
        float wa = lrexp2(*(const float*)(asc + (s0 * 16u + hb)) + adh);
        uint4 ua = *(const uint4*)(hlbc + (s0 * 128u + qb));
        acc[0] += wa * bflo(ua.x);
        acc[1] += wa * bfhi(ua.x);
        acc[2] += wa * bflo(ua.y);
        acc[3] += wa * bfhi(ua.y);
        acc[4] += wa * bflo(ua.z);
        acc[5] += wa * bfhi(ua.z);
        acc[6] += wa * bflo(ua.w);
        acc[7] += wa * bfhi(ua.w);
        z += wa;
    }
    // merge the 8 edge-groups (lanes with equal q)
    #pragma unroll
    for (int i = 0; i < 8; ++i) {
        acc[i] += __shfl_xor(acc[i], 8);
        acc[i] += __shfl_xor(acc[i], 16);
        acc[i] += __shfl_xor(acc[i], 32);
    }
    z += __shfl_xor(z, 8); z += __shfl_xor(z, 16); z += __shfl_xor(z, 32);
    float rz = 1.f / (z + 1e-16f);
    float4 bg0 = ((const float4*)bg)[2 * q];
    float4 bg1 = ((const float4*)bg)[2 * q + 1];
    float v[8];
    v[0] = acc[0] * rz + bg0.x; v[1] = acc[1] * rz + bg0.y;
    v[2] = acc[2] * rz + bg0.z; v[3] = acc[3] * rz + bg0.w;
    v[4] = acc[4] * rz + bg1.x; v[5] = acc[5] * rz + bg1.y;
    v[6] = acc[6] * rz + bg1.z; v[7] = acc[7] * rz + bg1.w;
    float ssum = 0.f;
    #pragma unroll
    for (int i = 0; i < 8; ++i) ssum += v[i];
    #pragma unroll
    for (int off = 1; off < 8; off <<= 1) ssum += __shfl_xor(ssum, off);
    float mu = ssum * (1.f / 64.f);
    float vs = 0.f;
    #pragma unroll
    for (int i = 0; i < 8; ++i) { v[i] -= mu; vs += v[i] * v[i]; }
    #pragma unroll
    for (int off = 1; off < 8; off <<= 1) vs += __shfl_xor(vs, off);
    float rstd = rsqrtf(vs * (1.f / 64.f) + LN_EPS);
    float4 g0 = ((const float4*)g)[2 * q];
    float4 g1 = ((const float4*)g)[2 * q + 1];
    float4 b0 = ((const float4*)b)[2 * q];
    float4 b1 = ((const float4*)b)[2 * q + 1];
    float4 h0 = ((const float4*)hres)[(size_t)n * 16 + 2 * q];
    float4 h1 = ((const float4*)hres)[(size_t)n * 16 + 2 * q + 1];
    float y[8];
    y[0] = fmaxf(v[0] * rstd * g0.x + b0.x, 0.f) + h0.x;
    y[1] = fmaxf(v[1] * rstd * g0.y + b0.y, 0.f) + h0.y;
    y[2] = fmaxf(v[2] * rstd * g0.z + b0.z, 0.f) + h0.z;
    y[3] = fmaxf(v[3] * rstd * g0.w + b0.w, 0.f) + h0.w;
    y[4] = fmaxf(v[4] * rstd * g1.x + b1.x, 0.f) + h1.x;
    y[5] = fmaxf(v[5] * rstd * g1.y + b1.y, 0.f) + h1.y;
    y[6] = fmaxf(v[6] * rstd * g1.z + b1.z, 0.f) + h1.z;
    y[7] = fmaxf(v[7] * rstd * g1.w + b1.w, 0.f) + h1.w;
    if (!last) {
        if (grp == 0) {
            float4 o0; o0.x = y[0]; o0.y = y[1]; o0.z = y[2]; o0.w = y[3];
            float4 o1; o1.x = y[4]; o1.y = y[5]; o1.z = y[6]; o1.w = y[7];
            ((float4*)hout)[(size_t)n * 16 + 2 * q] = o0;
            ((float4*)hout)[(size_t)n * 16 + 2 * q + 1] = o1;
        }
    } else {
        float4 w0 = ((const float4*)Wout)[2 * q];
        float4 w1 = ((const float4*)Wout)[2 * q + 1];
        float pp = y[0] * w0.x + y[1] * w0.y + y[2] * w0.z + y[3] * w0.w
                 + y[4] * w1.x + y[5] * w1.y + y[6] * w1.z + y[7] * w1.w;
        #pragma unroll
        for (int off = 1; off < 8; off <<= 1) pp += __shfl_xor(pp, off);
        if (lane == 0) out[n] = pp + bout[0];
    }
}

extern "C" void kernel_launch(void* const* d_in, const int* in_sizes, int n_in,
                              void* d_out, int out_size, void* d_ws, size_t ws_size,
                              hipStream_t stream) {
    const float* x     = (const float*)d_in[0];
    const int*   ei    = (const int*)  d_in[1];
    const float* Win   = (const float*)d_in[2];
    const float* bin_  = (const float*)d_in[3];
    const float* Wg    = (const float*)d_in[4];
    const float* att_s = (const float*)d_in[5];
    const float* att_d = (const float*)d_in[6];
    const float* bg    = (const float*)d_in[7];
    const float* lng   = (const float*)d_in[8];
    const float* lnb   = (const float*)d_in[9];
    const float* Wout  = (const float*)d_in[10];
    const float* bout  = (const float*)d_in[11];
    float* out = (float*)d_out;

    float* hA   = (float*)d_ws;                        // h (layer input / residual)
    float* hC   = hA + (size_t)N_NODES * 64;           // h (layer output)
    unsigned* hlb = (unsigned*)(hC + (size_t)N_NODES * 64);  // bf16x2 [N][32]
    float* as_  = (float*)(hlb + (size_t)N_NODES * 32);
    float* ad_  = as_ + (size_t)N_NODES * 4;
    int* row    = (int*)(ad_ + (size_t)N_NODES * 4);   // N+1
    int* bcnt   = row + (N_NODES + 1);                 // 1024
    int* bbase  = bcnt + NBUCK_PAD;                    // 1025
    int* bcur   = bbase + (NBUCK_PAD + 1);             // 1024
    int* ssrc   = bcur + NBUCK_PAD;                    // E
    unsigned* ebuf = (unsigned*)(ssrc + E_EDGES);      // E packed

    const int* srcp = ei;
    const int* dstp = ei + E_EDGES;

    hipMemsetAsync(bcnt, 0, NBUCK_PAD * sizeof(int), stream);
    k_bhist<<<256, 256, 0, stream>>>(dstp, bcnt);
    k_bscan<<<1, NBUCK_PAD, 0, stream>>>(bcnt, bbase, bcur);
    k_part<<<(E_EDGES + PART_CHUNK - 1) / PART_CHUNK, 256, 0, stream>>>(srcp, dstp, bcur, ebuf);
    k_fin<<<NBUCK, 256, 0, stream>>>(bbase, ebuf, row, ssrc);

    k_in_proj_fused<<<N_NODES / 32, 256, 0, stream>>>(
        x, Win, bin_, Wg, att_s, att_d, hA, hlb, as_, ad_);

    const int aggBlocks = (N_NODES * 64 + 255) / 256;
    for (int L = 0; L < 3; ++L) {
        if (L > 0) {
            k_gat_lin<<<N_NODES / 32, 256, 0, stream>>>(hA, Wg + L * 64 * 64,
                                                att_s + L * 64, att_d + L * 64,
                                                hlb, as_, ad_);
        }
        k_gat_agg<<<aggBlocks, 256, 0, stream>>>(row, ssrc, as_, ad_, hlb, hA,
                                                 bg + L * 64, lng + L * 64, lnb + L * 64,
                                                 hC, Wout, bout, out, (L == 2) ? 1 : 0);
        float* t = hA; hA = hC; hC = t;
    }
}